// Round 4
// baseline (347.442 us; speedup 1.0000x reference)
//
#include <hip/hip_runtime.h>
#include <hip/hip_bf16.h>
#include <stdint.h>

#define M_DIM 8192
#define K_DIM 2048
#define N_DIM 4096
#define BT 256
#define NT_M (M_DIM / BT)   // 32 m-tiles
#define NT_N (N_DIM / BT)   // 16 n-tiles
#define NKT (K_DIM / 64)    // 32 K-tiles of BK=64

typedef __hip_bfloat16 bf16;
typedef __attribute__((ext_vector_type(8))) short bf16x8;
typedef __attribute__((ext_vector_type(4))) float floatx4;

__device__ __forceinline__ void gload_lds16(const void* g, void* l) {
  __builtin_amdgcn_global_load_lds((const __attribute__((address_space(1))) void*)g,
                                   (__attribute__((address_space(3))) void*)l, 16, 0, 0);
}

// ---------------- Kernel 0: fp32 -> bf16 convert (x then W), 8 elems/thread ----
__global__ __launch_bounds__(256) void convert_kernel(
    const float* __restrict__ x, const float* __restrict__ W,
    bf16* __restrict__ xb, bf16* __restrict__ wb) {
  int idx = blockIdx.x * 256 + threadIdx.x;
  int e = idx * 8;
  const int NX = M_DIM * K_DIM;  // 16,777,216
  const float* src;
  bf16* dst;
  if (e < NX) { src = x + e; dst = xb + e; }
  else        { src = W + (e - NX); dst = wb + (e - NX); }
  const float4* s4 = (const float4*)src;
  float4 a = s4[0];
  float4 c = s4[1];
  union { bf16 h[8]; uint4 u; } o;
  o.h[0] = __float2bfloat16(a.x); o.h[1] = __float2bfloat16(a.y);
  o.h[2] = __float2bfloat16(a.z); o.h[3] = __float2bfloat16(a.w);
  o.h[4] = __float2bfloat16(c.x); o.h[5] = __float2bfloat16(c.y);
  o.h[6] = __float2bfloat16(c.z); o.h[7] = __float2bfloat16(c.w);
  *(uint4*)dst = o.u;
}

// ---------------- Kernel 1: 256x256 8-phase pipelined GEMM (C^T) + GN + min ----
// Phase = {vmcnt?; barrier; reads(<=8); stage; lgkmcnt(N); 16 MFMA}.
// Staging margins: k2 staged p3/p4, k3 staged p7/p8; every vmcnt(4) rendezvous
// confirms halves staged 4 phases earlier (>= 2400 cyc > HBM latency).
// Every stage-issue is one barrier after its readers' lgkm-confirm.

#define BARX() __builtin_amdgcn_s_barrier()
#define SB0()  __builtin_amdgcn_sched_barrier(0)
#define LGKMW(n) do { asm volatile("s_waitcnt lgkmcnt(" n ")" ::: "memory"); \
                      __builtin_amdgcn_sched_barrier(0); } while (0)
#define VMW(n)   do { asm volatile("s_waitcnt vmcnt(" n ")" ::: "memory"); \
                      __builtin_amdgcn_sched_barrier(0); } while (0)

// stage one half-tile (128 rows x 64 k) of one matrix: 2 gload_lds per wave
#define STG2(gp, kt, hh, dp) do { \
  gload_lds16((gp) + ((hh) * 128 + 0) * K_DIM + (kt) * 64, (void*)((dp) + (hh) * 8192)); \
  gload_lds16((gp) + ((hh) * 128 + 8) * K_DIM + (kt) * 64, (void*)((dp) + (hh) * 8192 + 512)); \
} while (0)

// frag reads; swk* carries the XOR bank swizzle
#define RD_A0(rp) do { _Pragma("unroll") for (int i2 = 0; i2 < 4; ++i2) { \
  af0[i2][0] = *(const bf16x8*)((rp) + (i2 * 16) * 64 + swk0); \
  af0[i2][1] = *(const bf16x8*)((rp) + (i2 * 16) * 64 + swk1); } } while (0)
#define RD_A1a(rp) do { _Pragma("unroll") for (int i2 = 0; i2 < 2; ++i2) { \
  af1[i2][0] = *(const bf16x8*)((rp) + (64 + i2 * 16) * 64 + swk0); \
  af1[i2][1] = *(const bf16x8*)((rp) + (64 + i2 * 16) * 64 + swk1); } } while (0)
#define RD_A1b(rp) do { _Pragma("unroll") for (int i2 = 2; i2 < 4; ++i2) { \
  af1[i2][0] = *(const bf16x8*)((rp) + (64 + i2 * 16) * 64 + swk0); \
  af1[i2][1] = *(const bf16x8*)((rp) + (64 + i2 * 16) * 64 + swk1); } } while (0)
#define RD_B01(rp, B) do { _Pragma("unroll") for (int j2 = 0; j2 < 2; ++j2) { \
  B[j2][0] = *(const bf16x8*)((rp) + (j2 * 16) * 64 + swk0); \
  B[j2][1] = *(const bf16x8*)((rp) + (j2 * 16) * 64 + swk1); } } while (0)
#define RD_B23(rp) do { _Pragma("unroll") for (int j2 = 0; j2 < 2; ++j2) { \
  b23[j2][0] = *(const bf16x8*)((rp) + ((2 + j2) * 16) * 64 + swk0); \
  b23[j2][1] = *(const bf16x8*)((rp) + ((2 + j2) * 16) * 64 + swk1); } } while (0)

#define MFQ(i0, j0, A, B) do { \
  __builtin_amdgcn_s_setprio(1); \
  _Pragma("unroll") for (int i2 = 0; i2 < 4; ++i2) \
  _Pragma("unroll") for (int j2 = 0; j2 < 2; ++j2) { \
    acc[(i0) + i2][(j0) + j2] = __builtin_amdgcn_mfma_f32_16x16x32_bf16( \
        A[i2][0], B[j2][0], acc[(i0) + i2][(j0) + j2], 0, 0, 0); \
    acc[(i0) + i2][(j0) + j2] = __builtin_amdgcn_mfma_f32_16x16x32_bf16( \
        A[i2][1], B[j2][1], acc[(i0) + i2][(j0) + j2], 0, 0, 0); } \
  __builtin_amdgcn_s_setprio(0); } while (0)

__global__ __launch_bounds__(512, 2) void gemm_gn_min(
    const bf16* __restrict__ xb, const bf16* __restrict__ wb,
    const float* __restrict__ bgemm, float* __restrict__ pmin) {
  __shared__ bf16 sA[32768];   // [2][256*64] W tiles (A-operand), 64 KiB
  __shared__ bf16 sB[32768];   // [2][256*64] x tiles (B-operand), 64 KiB

  const int tid  = threadIdx.x;
  const int lane = tid & 63;
  const int wid  = tid >> 6;      // 0..7
  const int wr   = wid >> 2;      // n-half (0..1): rows wr*128..+127
  const int wc   = wid & 3;       // m-quarter (0..3): cols wc*64..+63
  const int q    = lane >> 4;     // quad 0..3
  const int c    = lane & 15;

  const int mTile = blockIdx.x & (NT_M - 1);
  const int nTile = blockIdx.x >> 5;
  const int mBase = mTile * BT;
  const int nBase = nTile * BT;

  // staging map: lane -> (row-in-8-chunk, xor-swizzled k-chunk on GLOBAL col)
  const int ldRow = lane >> 3;
  const int swz   = ((lane & 7) ^ ldRow) * 8;
  // read-side swizzle (chunk = (ks*4+q) ^ (row&7); row&7 == c&7 here)
  const int swk0 = (q ^ (c & 7)) * 8;
  const int swk1 = ((4 + q) ^ (c & 7)) * 8;

  // per-wave global staging bases (wave covers rows wid*16 + ldRow + {0,8})
  const bf16* gA = wb + (size_t)(nBase + wid * 16 + ldRow) * K_DIM + swz;
  const bf16* gB = xb + (size_t)(mBase + wid * 16 + ldRow) * K_DIM + swz;
  // per-wave LDS dest bases (buf0); buf1 = +16384 elems
  bf16* dA = sA + wid * 1024;
  bf16* dB = sB + wid * 1024;
  // per-lane LDS read bases
  const bf16* rA0 = sA + (wr * 128 + c) * 64;
  const bf16* rA1 = rA0 + 16384;
  const bf16* rB0 = sB + (wc * 64 + c) * 64;
  const bf16* rB1 = rB0 + 16384;

  floatx4 acc[8][4];
#pragma unroll
  for (int i = 0; i < 8; ++i)
#pragma unroll
    for (int j = 0; j < 4; ++j) acc[i][j] = (floatx4){0.f, 0.f, 0.f, 0.f};

  // frag banks. af0/af1 single banks (re-read >=1 phase after last use);
  // b01a/b01b alternate by K-tile parity; b23 single bank.
  bf16x8 af0[4][2], af1[4][2], b01a[2][2], b01b[2][2], b23[2][2];

  // ---- prologue: stage k0 (b0) + k1 (b1); confirm k0; read k0's af0+b01a.
  STG2(gB, 0, 0, dB); STG2(gB, 0, 1, dB);                  // k0.B
  STG2(gA, 0, 0, dA); STG2(gA, 0, 1, dA);                  // k0.A
  STG2(gB, 1, 0, dB + 16384); STG2(gB, 1, 1, dB + 16384);  // k1.B
  STG2(gA, 1, 0, dA + 16384); STG2(gA, 1, 1, dA + 16384);  // k1.A
  VMW("8");           // confirms k0.B + k0.A; leaves k1.B,k1.A in flight
  BARX();
  RD_B01(rB0, b01a); RD_A0(rA0); SB0();   // 12 reads outstanding

  // ---- main loop: iter i computes k0=2i (buf0) and k1=2i+1 (buf1);
  // stages k2 -> buf0 at p3/p4, k3 -> buf1 at p7/p8. vmcnt(4) at p3/p4/p7/p8
  // confirms halves staged 4 phases earlier. Max ds-read batch = 8.
#pragma unroll 1
  for (int i = 0; i < NKT / 2 - 1; ++i) {
    const int k2 = 2 * i + 2, k3 = 2 * i + 3;
    // p1: confirm b01a+af0 (12 old); MFQ(0,0)
    BARX();
    RD_B23(rB0); RD_A1a(rA0); SB0();
    LGKMW("8"); MFQ(0, 0, af0, b01a);
    // p2: confirm b23; MFQ(0,2)
    BARX();
    RD_A1b(rA0); SB0();
    LGKMW("8"); MFQ(0, 2, af0, b23);
    // p3: rendezvous k1.B; read b01b(k1); stage k2.B; confirm af1; MFQ(4,2)
    VMW("4"); BARX();
    RD_B01(rB1, b01b); SB0();
    STG2(gB, k2, 0, dB); STG2(gB, k2, 1, dB); SB0();
    LGKMW("4"); MFQ(4, 2, af1, b23);
    // p4: rendezvous k1.A; read af0(k1); stage k2.A; MFQ(4,0) (operands old)
    VMW("4"); BARX();
    RD_A0(rA1); SB0();
    STG2(gA, k2, 0, dA); STG2(gA, k2, 1, dA); SB0();
    MFQ(4, 0, af1, b01a);
    // p5: confirm b01b+af0(k1); MFQ(0,0)
    BARX();
    RD_B23(rB1); RD_A1a(rA1); SB0();
    LGKMW("8"); MFQ(0, 0, af0, b01b);
    // p6: confirm b23(k1); MFQ(0,2)
    BARX();
    RD_A1b(rA1); SB0();
    LGKMW("8"); MFQ(0, 2, af0, b23);
    // p7: rendezvous k2.B; read b01a(k2); stage k3.B; confirm af1(k1); MFQ(4,2)
    VMW("4"); BARX();
    RD_B01(rB0, b01a); SB0();
    STG2(gB, k3, 0, dB + 16384); STG2(gB, k3, 1, dB + 16384); SB0();
    LGKMW("4"); MFQ(4, 2, af1, b23);
    // p8: rendezvous k2.A; read af0(k2); stage k3.A; MFQ(4,0)
    VMW("4"); BARX();
    RD_A0(rA0); SB0();
    STG2(gA, k3, 0, dA + 16384); STG2(gA, k3, 1, dA + 16384); SB0();
    MFQ(4, 0, af1, b01b);
  }

  // ---- epilogue: tiles 30 (buf0) and 31 (buf1); no staging; drain vm at e3/e4
  // e1
  BARX();
  RD_B23(rB0); RD_A1a(rA0); SB0();
  LGKMW("8"); MFQ(0, 0, af0, b01a);
  // e2
  BARX();
  RD_A1b(rA0); SB0();
  LGKMW("8"); MFQ(0, 2, af0, b23);
  // e3: confirm k31.B
  VMW("4"); BARX();
  RD_B01(rB1, b01b); SB0();
  LGKMW("4"); MFQ(4, 2, af1, b23);
  // e4: confirm k31.A (vm drained)
  VMW("0"); BARX();
  RD_A0(rA1); SB0();
  MFQ(4, 0, af1, b01a);
  // e5
  BARX();
  RD_B23(rB1); RD_A1a(rA1); SB0();
  LGKMW("8"); MFQ(0, 0, af0, b01b);
  // e6
  BARX();
  RD_A1b(rA1); SB0();
  LGKMW("8"); MFQ(0, 2, af0, b23);
  // e7
  BARX();
  LGKMW("0"); MFQ(4, 2, af1, b23);
  // e8
  MFQ(4, 0, af1, b01b);

  // ---- fused epilogue: +b, groupnorm over 8 consecutive n, min over n per m
  float colmin[4] = {3.4e38f, 3.4e38f, 3.4e38f, 3.4e38f};
#pragma unroll
  for (int i = 0; i < 8; ++i) {
    const float* bp = bgemm + nBase + wr * 128 + i * 16 + q * 4;
    float b0 = bp[0], b1 = bp[1], b2 = bp[2], b3 = bp[3];
#pragma unroll
    for (int j = 0; j < 4; ++j) {
      float v0 = acc[i][j][0] + b0;
      float v1 = acc[i][j][1] + b1;
      float v2 = acc[i][j][2] + b2;
      float v3 = acc[i][j][3] + b3;
      float s  = (v0 + v1) + (v2 + v3);
      float ss = (v0 * v0 + v1 * v1) + (v2 * v2 + v3 * v3);
      // partner quad (lane^16) holds the other 4 n's of this group of 8
      s  += __shfl_xor(s, 16);
      ss += __shfl_xor(ss, 16);
      float mean = s * 0.125f;
      float var  = ss * 0.125f - mean * mean;
      float inv  = rsqrtf(var + 1e-5f);          // inv > 0, so min commutes
      float mndev = fminf(fminf(v0, v1), fminf(v2, v3)) - mean;
      colmin[j] = fminf(colmin[j], mndev * inv);
    }
  }
#pragma unroll
  for (int j = 0; j < 4; ++j) {
    float m0 = colmin[j];
    m0 = fminf(m0, __shfl_xor(m0, 16));
    m0 = fminf(m0, __shfl_xor(m0, 32));
    colmin[j] = m0;
  }
  // LDS tiles are dead now; reuse the front of sA for the 2x256 partial mins.
  float* sm = (float*)sA;
  __syncthreads();
  if (q == 0) {
#pragma unroll
    for (int j = 0; j < 4; ++j)
      sm[wr * 256 + wc * 64 + j * 16 + c] = colmin[j];
  }
  __syncthreads();
  if (tid < 256) {
    float p = fminf(sm[tid], sm[256 + tid]);
    pmin[(size_t)(mBase + tid) * NT_N + nTile] = p;   // one writer per slot
  }
}

// ---------------- Kernel 2: out[m, n] = rowmin[m] + bias[n] -------------------
__global__ __launch_bounds__(256) void out_kernel(
    const float* __restrict__ pmin, const float* __restrict__ bias,
    float* __restrict__ out) {
  const int m = blockIdx.x;
  const int tid = threadIdx.x;
  __shared__ float srow;
  if (tid < 64) {
    float v = (tid < NT_N) ? pmin[m * NT_N + tid] : 3.4e38f;
    v = fminf(v, __shfl_xor(v, 1));
    v = fminf(v, __shfl_xor(v, 2));
    v = fminf(v, __shfl_xor(v, 4));
    v = fminf(v, __shfl_xor(v, 8));
    v = fminf(v, __shfl_xor(v, 16));
    if (tid == 0) srow = v;
  }
  __syncthreads();
  const float rmin = srow;
  const float4* b4 = (const float4*)bias;
  float4* o4 = (float4*)(out + (size_t)m * N_DIM);
#pragma unroll
  for (int it = 0; it < 4; ++it) {
    int idx2 = it * 256 + tid;
    float4 bb = b4[idx2];
    o4[idx2] = (float4){rmin + bb.x, rmin + bb.y, rmin + bb.z, rmin + bb.w};
  }
}

extern "C" void kernel_launch(void* const* d_in, const int* in_sizes, int n_in,
                              void* d_out, int out_size, void* d_ws, size_t ws_size,
                              hipStream_t stream) {
  const float* x    = (const float*)d_in[0];
  const float* W    = (const float*)d_in[1];
  const float* b    = (const float*)d_in[2];
  const float* bias = (const float*)d_in[3];
  float* out = (float*)d_out;

  // bf16 scratch lives in d_out (134 MB >> 50 MB needed); overwritten at the end.
  bf16* xb = (bf16*)d_out;
  bf16* wb = (bf16*)((char*)d_out + (size_t)M_DIM * K_DIM * sizeof(bf16));
  float* pmin = (float*)d_ws;  // 8192 * 16 * 4 = 512 KiB of workspace

  convert_kernel<<<(M_DIM * K_DIM + N_DIM * K_DIM) / (8 * 256), 256, 0, stream>>>(x, W, xb, wb);
  gemm_gn_min<<<NT_M * NT_N, 512, 0, stream>>>(xb, wb, b, pmin);
  out_kernel<<<M_DIM, 256, 0, stream>>>(pmin, bias, out);
}

// Round 5
// 329.376 us; speedup vs baseline: 1.0548x; 1.0548x over previous
//
#include <hip/hip_runtime.h>
#include <hip/hip_bf16.h>
#include <stdint.h>

#define M_DIM 8192
#define K_DIM 2048
#define N_DIM 4096
#define BT 256
#define NT_M (M_DIM / BT)   // 32 m-tiles
#define NT_N (N_DIM / BT)   // 16 n-tiles
#define NKT (K_DIM / 64)    // 32 K-tiles of BK=64

typedef __hip_bfloat16 bf16;
typedef __attribute__((ext_vector_type(8))) short bf16x8;
typedef __attribute__((ext_vector_type(4))) float floatx4;

__device__ __forceinline__ void gload_lds16(const void* g, void* l) {
  __builtin_amdgcn_global_load_lds((const __attribute__((address_space(1))) void*)g,
                                   (__attribute__((address_space(3))) void*)l, 16, 0, 0);
}

// ---------------- Kernel 0: fp32 -> bf16 convert (x then W), 8 elems/thread ----
__global__ __launch_bounds__(256) void convert_kernel(
    const float* __restrict__ x, const float* __restrict__ W,
    bf16* __restrict__ xb, bf16* __restrict__ wb) {
  int idx = blockIdx.x * 256 + threadIdx.x;
  int e = idx * 8;
  const int NX = M_DIM * K_DIM;  // 16,777,216
  const float* src;
  bf16* dst;
  if (e < NX) { src = x + e; dst = xb + e; }
  else        { src = W + (e - NX); dst = wb + (e - NX); }
  const float4* s4 = (const float4*)src;
  float4 a = s4[0];
  float4 c = s4[1];
  union { bf16 h[8]; uint4 u; } o;
  o.h[0] = __float2bfloat16(a.x); o.h[1] = __float2bfloat16(a.y);
  o.h[2] = __float2bfloat16(a.z); o.h[3] = __float2bfloat16(a.w);
  o.h[4] = __float2bfloat16(c.x); o.h[5] = __float2bfloat16(c.y);
  o.h[6] = __float2bfloat16(c.z); o.h[7] = __float2bfloat16(c.w);
  *(uint4*)dst = o.u;
}

// ---------------- Kernel 1: 256x256 8-phase pipelined GEMM (C^T) + GN + min ----
// Round-3 structure (reads issued BEFORE the phase barrier so they drain under
// the barrier-arrival stagger; counted lgkm waits; vmcnt(2) at p4/p8 only).
// Single delta vs round 3: A-halves staged one phase EARLIER (p2/p6 stage both
// halves; p3/p7 stage nothing) so the tightest staging->vmcnt margin is 2
// MFMA-phases (~1240 cyc > ~900 cyc HBM latency) instead of 1.

#define BARX() __builtin_amdgcn_s_barrier()
#define SB0()  __builtin_amdgcn_sched_barrier(0)
#define LGKMW(n) do { asm volatile("s_waitcnt lgkmcnt(" n ")" ::: "memory"); \
                      __builtin_amdgcn_sched_barrier(0); } while (0)
#define VMW(n)   do { asm volatile("s_waitcnt vmcnt(" n ")" ::: "memory"); \
                      __builtin_amdgcn_sched_barrier(0); } while (0)

// stage one half-tile (128 rows x 64 k) of one matrix: 2 gload_lds per wave
#define STG2(gp, kt, hh, dp) do { \
  gload_lds16((gp) + ((hh) * 128 + 0) * K_DIM + (kt) * 64, (void*)((dp) + (hh) * 8192)); \
  gload_lds16((gp) + ((hh) * 128 + 8) * K_DIM + (kt) * 64, (void*)((dp) + (hh) * 8192 + 512)); \
} while (0)

// frag reads (8-per A-half, 4-per B-pair); swk* carries the XOR bank swizzle
#define RD_A0(rp) do { _Pragma("unroll") for (int i2 = 0; i2 < 4; ++i2) { \
  af0[i2][0] = *(const bf16x8*)((rp) + (i2 * 16) * 64 + swk0); \
  af0[i2][1] = *(const bf16x8*)((rp) + (i2 * 16) * 64 + swk1); } } while (0)
#define RD_A1(rp) do { _Pragma("unroll") for (int i2 = 0; i2 < 4; ++i2) { \
  af1[i2][0] = *(const bf16x8*)((rp) + (64 + i2 * 16) * 64 + swk0); \
  af1[i2][1] = *(const bf16x8*)((rp) + (64 + i2 * 16) * 64 + swk1); } } while (0)
#define RD_B01(rp, B) do { _Pragma("unroll") for (int j2 = 0; j2 < 2; ++j2) { \
  B[j2][0] = *(const bf16x8*)((rp) + (j2 * 16) * 64 + swk0); \
  B[j2][1] = *(const bf16x8*)((rp) + (j2 * 16) * 64 + swk1); } } while (0)
#define RD_B23(rp) do { _Pragma("unroll") for (int j2 = 0; j2 < 2; ++j2) { \
  b23[j2][0] = *(const bf16x8*)((rp) + ((2 + j2) * 16) * 64 + swk0); \
  b23[j2][1] = *(const bf16x8*)((rp) + ((2 + j2) * 16) * 64 + swk1); } } while (0)

#define MFQ(i0, j0, A, B) do { \
  __builtin_amdgcn_s_setprio(1); \
  _Pragma("unroll") for (int i2 = 0; i2 < 4; ++i2) \
  _Pragma("unroll") for (int j2 = 0; j2 < 2; ++j2) { \
    acc[(i0) + i2][(j0) + j2] = __builtin_amdgcn_mfma_f32_16x16x32_bf16( \
        A[i2][0], B[j2][0], acc[(i0) + i2][(j0) + j2], 0, 0, 0); \
    acc[(i0) + i2][(j0) + j2] = __builtin_amdgcn_mfma_f32_16x16x32_bf16( \
        A[i2][1], B[j2][1], acc[(i0) + i2][(j0) + j2], 0, 0, 0); } \
  __builtin_amdgcn_s_setprio(0); } while (0)

__global__ __launch_bounds__(512, 2) void gemm_gn_min(
    const bf16* __restrict__ xb, const bf16* __restrict__ wb,
    const float* __restrict__ bgemm, float* __restrict__ pmin) {
  __shared__ bf16 sA[32768];   // [2][256*64] W tiles (A-operand), 64 KiB
  __shared__ bf16 sB[32768];   // [2][256*64] x tiles (B-operand), 64 KiB

  const int tid  = threadIdx.x;
  const int lane = tid & 63;
  const int wid  = tid >> 6;      // 0..7
  const int wr   = wid >> 2;      // n-half (0..1): rows wr*128..+127
  const int wc   = wid & 3;      // m-quarter (0..3): cols wc*64..+63
  const int q    = lane >> 4;     // quad 0..3
  const int c    = lane & 15;

  const int mTile = blockIdx.x & (NT_M - 1);
  const int nTile = blockIdx.x >> 5;
  const int mBase = mTile * BT;
  const int nBase = nTile * BT;

  // staging map: lane -> (row-in-8-chunk, xor-swizzled k-chunk on GLOBAL col)
  const int ldRow = lane >> 3;
  const int swz   = ((lane & 7) ^ ldRow) * 8;
  // read-side swizzle (chunk = (ks*4+q) ^ (row&7); row&7 == c&7 here)
  const int swk0 = (q ^ (c & 7)) * 8;
  const int swk1 = ((4 + q) ^ (c & 7)) * 8;

  // per-wave global staging bases (wave covers rows wid*16 + ldRow + {0,8})
  const bf16* gA = wb + (size_t)(nBase + wid * 16 + ldRow) * K_DIM + swz;
  const bf16* gB = xb + (size_t)(mBase + wid * 16 + ldRow) * K_DIM + swz;
  // per-wave LDS dest bases (buf0); buf1 = +16384 elems
  bf16* dA = sA + wid * 1024;
  bf16* dB = sB + wid * 1024;
  // per-lane LDS read bases
  const bf16* rA0 = sA + (wr * 128 + c) * 64;
  const bf16* rA1 = rA0 + 16384;
  const bf16* rB0 = sB + (wc * 64 + c) * 64;
  const bf16* rB1 = rB0 + 16384;

  floatx4 acc[8][4];
#pragma unroll
  for (int i = 0; i < 8; ++i)
#pragma unroll
    for (int j = 0; j < 4; ++j) acc[i][j] = (floatx4){0.f, 0.f, 0.f, 0.f};

  // frag register banks. af0/af1: A-halves of current K-tile. b01a/b01b:
  // alternating banks for B rows 0-31. b23: single bank.
  bf16x8 af0[4][2], af1[4][2], b01a[2][2], b01b[2][2], b23[2][2];

  // ---- prologue: tile 0 full + tile 1 B-half0; 2 staging instrs stay in flight
  STG2(gB, 0, 0, dB); STG2(gB, 0, 1, dB);
  STG2(gA, 0, 0, dA); STG2(gA, 0, 1, dA);
  STG2(gB, 1, 0, dB + 16384);
  VMW("2");
  BARX();
  RD_A0(rA0); RD_B01(rB0, b01a); SB0();

  // ---- main loop: iter i computes K-tiles 2i (buf0, p1-4) and 2i+1 (buf1,
  // p5-8). Staging: p1:b1.Bh1<-k1 p2:b1.Ah0+b1.Ah1<-k1 p3:- p4:b0.Bh0<-k2
  // p5:b0.Bh1 p6:b0.Ah0+b0.Ah1 p7:- p8:b1.Bh0<-k3. vmcnt(2) at p4/p8 only;
  // tightest margin now 2 phases (Ah1 staged p2, confirmed p4). Each body
  // issues next phase's frags; wait lgkmcnt(#issued) after the barrier.
#pragma unroll 1
  for (int i = 0; i < NKT / 2 - 1; ++i) {
    const int k1 = 2 * i + 1, k2 = 2 * i + 2, k3 = 2 * i + 3;
    // p1
    RD_B23(rB0); SB0();
    STG2(gB, k1, 1, dB + 16384); SB0();
    BARX(); LGKMW("4"); MFQ(0, 0, af0, b01a);
    // p2: stage BOTH A-halves of k1 (margin 2 at p4's vmcnt)
    RD_A1(rA0); SB0();
    STG2(gA, k1, 0, dA + 16384); STG2(gA, k1, 1, dA + 16384); SB0();
    BARX(); LGKMW("8"); MFQ(0, 2, af0, b23);
    // p3: no staging
    BARX(); LGKMW("0"); MFQ(4, 2, af1, b23);
    // p4: rendezvous for buf1 (tile k1) readiness, then cross-buffer read-ahead
    STG2(gB, k2, 0, dB); VMW("2");
    BARX();
    RD_A0(rA1); RD_B01(rB1, b01b); SB0();
    MFQ(4, 0, af1, b01a);
    // p5
    RD_B23(rB1); SB0();
    STG2(gB, k2, 1, dB); SB0();
    BARX(); LGKMW("4"); MFQ(0, 0, af0, b01b);
    // p6: stage BOTH A-halves of k2
    RD_A1(rA1); SB0();
    STG2(gA, k2, 0, dA); STG2(gA, k2, 1, dA); SB0();
    BARX(); LGKMW("8"); MFQ(0, 2, af0, b23);
    // p7: no staging
    BARX(); LGKMW("0"); MFQ(4, 2, af1, b23);
    // p8: rendezvous for buf0 (tile k2) readiness
    STG2(gB, k3, 0, dB + 16384); VMW("2");
    BARX();
    RD_A0(rA0); RD_B01(rB0, b01a); SB0();
    MFQ(4, 0, af1, b01b);
  }

  // ---- epilogue: tiles 30 (buf0) and 31 (buf1); drain staging at e4
  // e1
  RD_B23(rB0); SB0();
  STG2(gB, NKT - 1, 1, dB + 16384); SB0();
  BARX(); LGKMW("4"); MFQ(0, 0, af0, b01a);
  // e2: stage BOTH A-halves of tile 31
  RD_A1(rA0); SB0();
  STG2(gA, NKT - 1, 0, dA + 16384); STG2(gA, NKT - 1, 1, dA + 16384); SB0();
  BARX(); LGKMW("8"); MFQ(0, 2, af0, b23);
  // e3: no staging
  BARX(); LGKMW("0"); MFQ(4, 2, af1, b23);
  // e4: all outstanding staging instrs belong to tile 31 -> drain fully
  VMW("0");
  BARX();
  RD_A0(rA1); RD_B01(rB1, b01b); SB0();
  MFQ(4, 0, af1, b01a);
  // e5
  RD_B23(rB1); SB0();
  BARX(); LGKMW("4"); MFQ(0, 0, af0, b01b);
  // e6
  RD_A1(rA1); SB0();
  BARX(); LGKMW("8"); MFQ(0, 2, af0, b23);
  // e7
  BARX(); LGKMW("0"); MFQ(4, 2, af1, b23);
  // e8
  MFQ(4, 0, af1, b01b);

  // ---- fused epilogue: +b, groupnorm over 8 consecutive n, min over n per m
  float colmin[4] = {3.4e38f, 3.4e38f, 3.4e38f, 3.4e38f};
#pragma unroll
  for (int i = 0; i < 8; ++i) {
    const float* bp = bgemm + nBase + wr * 128 + i * 16 + q * 4;
    float b0 = bp[0], b1 = bp[1], b2 = bp[2], b3 = bp[3];
#pragma unroll
    for (int j = 0; j < 4; ++j) {
      float v0 = acc[i][j][0] + b0;
      float v1 = acc[i][j][1] + b1;
      float v2 = acc[i][j][2] + b2;
      float v3 = acc[i][j][3] + b3;
      float s  = (v0 + v1) + (v2 + v3);
      float ss = (v0 * v0 + v1 * v1) + (v2 * v2 + v3 * v3);
      // partner quad (lane^16) holds the other 4 n's of this group of 8
      s  += __shfl_xor(s, 16);
      ss += __shfl_xor(ss, 16);
      float mean = s * 0.125f;
      float var  = ss * 0.125f - mean * mean;
      float inv  = rsqrtf(var + 1e-5f);          // inv > 0, so min commutes
      float mndev = fminf(fminf(v0, v1), fminf(v2, v3)) - mean;
      colmin[j] = fminf(colmin[j], mndev * inv);
    }
  }
#pragma unroll
  for (int j = 0; j < 4; ++j) {
    float m0 = colmin[j];
    m0 = fminf(m0, __shfl_xor(m0, 16));
    m0 = fminf(m0, __shfl_xor(m0, 32));
    colmin[j] = m0;
  }
  // LDS tiles are dead now; reuse the front of sA for the 2x256 partial mins.
  float* sm = (float*)sA;
  __syncthreads();
  if (q == 0) {
#pragma unroll
    for (int j = 0; j < 4; ++j)
      sm[wr * 256 + wc * 64 + j * 16 + c] = colmin[j];
  }
  __syncthreads();
  if (tid < 256) {
    float p = fminf(sm[tid], sm[256 + tid]);
    pmin[(size_t)(mBase + tid) * NT_N + nTile] = p;   // one writer per slot
  }
}

// ---------------- Kernel 2: out[m, n] = rowmin[m] + bias[n] -------------------
__global__ __launch_bounds__(256) void out_kernel(
    const float* __restrict__ pmin, const float* __restrict__ bias,
    float* __restrict__ out) {
  const int m = blockIdx.x;
  const int tid = threadIdx.x;
  __shared__ float srow;
  if (tid < 64) {
    float v = (tid < NT_N) ? pmin[m * NT_N + tid] : 3.4e38f;
    v = fminf(v, __shfl_xor(v, 1));
    v = fminf(v, __shfl_xor(v, 2));
    v = fminf(v, __shfl_xor(v, 4));
    v = fminf(v, __shfl_xor(v, 8));
    v = fminf(v, __shfl_xor(v, 16));
    if (tid == 0) srow = v;
  }
  __syncthreads();
  const float rmin = srow;
  const float4* b4 = (const float4*)bias;
  float4* o4 = (float4*)(out + (size_t)m * N_DIM);
#pragma unroll
  for (int it = 0; it < 4; ++it) {
    int idx2 = it * 256 + tid;
    float4 bb = b4[idx2];
    o4[idx2] = (float4){rmin + bb.x, rmin + bb.y, rmin + bb.z, rmin + bb.w};
  }
}

extern "C" void kernel_launch(void* const* d_in, const int* in_sizes, int n_in,
                              void* d_out, int out_size, void* d_ws, size_t ws_size,
                              hipStream_t stream) {
  const float* x    = (const float*)d_in[0];
  const float* W    = (const float*)d_in[1];
  const float* b    = (const float*)d_in[2];
  const float* bias = (const float*)d_in[3];
  float* out = (float*)d_out;

  // bf16 scratch lives in d_out (134 MB >> 50 MB needed); overwritten at the end.
  bf16* xb = (bf16*)d_out;
  bf16* wb = (bf16*)((char*)d_out + (size_t)M_DIM * K_DIM * sizeof(bf16));
  float* pmin = (float*)d_ws;  // 8192 * 16 * 4 = 512 KiB of workspace

  convert_kernel<<<(M_DIM * K_DIM + N_DIM * K_DIM) / (8 * 256), 256, 0, stream>>>(x, W, xb, wb);
  gemm_gn_min<<<NT_M * NT_N, 512, 0, stream>>>(xb, wb, b, pmin);
  out_kernel<<<M_DIM, 256, 0, stream>>>(pmin, bias, out);
}